// Round 6
// baseline (1202.682 us; speedup 1.0000x reference)
//
#include <hip/hip_runtime.h>
#include <math.h>

#define Bn 2
#define Cn 192
#define Dn 48
#define Hn 48
#define Wn 48
#define C4 768
#define DHW (Dn*Hn*Wn)          // 110592 per batch
#define CDHW ((long)Cn*DHW)     // 21233664 per batch

typedef __attribute__((ext_vector_type(8))) short bf16x8;
typedef __attribute__((ext_vector_type(4))) float f32x4;
typedef __attribute__((ext_vector_type(2))) float f32x2;

__device__ inline float bf2f(unsigned short u) {
    union { float f; unsigned int i; } v; v.i = ((unsigned int)u) << 16; return v.f;
}
__device__ inline unsigned short f2bf(float f) {
    union { float f; unsigned int i; } v; v.f = f;
    unsigned int r = v.i + 0x7FFFu + ((v.i >> 16) & 1u);   // RNE
    return (unsigned short)(r >> 16);
}
__device__ inline f32x2 dup2(unsigned int bits) {
    union { float f; unsigned int i; } v; v.i = bits;
    return (f32x2){v.f, v.f};
}

// ---------------- depthwise conv 7x7x7, packed-FMA, per-batch NCDHW -> NCDHW ----
// block: 128 threads, one channel, 16(d)x16(h)x16(w) output tile.
// thread: 4(d)x8(w) outputs as two float2 (d-pair) accumulators; v_pk_fma_f32.
// halo 22x22x22 bf16, row stride 28 shorts (56B = 14 banks -> 16 distinct
// start banks across the 16 hh lanes; <=2-way residual aliasing).
#define CT 16
#define CHD (CT+6)    // 22
#define CHH (CT+6)    // 22
#define CHWS 28       // padded w stride in shorts

__global__ __launch_bounds__(128)
void conv_dw(const float* __restrict__ x, const float* __restrict__ cw,
             const float* __restrict__ cb, float* __restrict__ yc)
{
    __shared__ unsigned short xt[CHD][CHH][CHWS];  // 27,104 B
    __shared__ f32x2 wp[8][7][7];                  //  3,136 B
    int c = blockIdx.y;
    int s = blockIdx.x;                   // 27 spatial tiles: 3(d) x 3(h) x 3(w)
    int wt = s % 3, ht = (s / 3) % 3, dt = s / 9;
    int d0 = dt * CT, h0 = ht * CT, w0 = wt * CT;
    int tid = threadIdx.x;

    // weight-pair table: wp[s][kh][kw] = (w[s], w[s-1]) with 0 pad at ends
    for (int i = tid; i < 392; i += 128) {
        int kw = i % 7, kh = (i / 7) % 7, sv = i / 49;
        float lo = (sv < 7) ? cw[((sv * 7 + kh) * 7 + kw) * Cn + c] : 0.0f;
        float hi = (sv >= 1) ? cw[(((sv - 1) * 7 + kh) * 7 + kw) * Cn + c] : 0.0f;
        wp[sv][kh][kw] = (f32x2){lo, hi};
    }

    // stage halo (bf16 pairs)
    const float* xb = x + (long)c * DHW;
    for (int u = tid; u < CHD * CHH * (CHWS / 2); u += 128) {
        int pair = u % (CHWS / 2);
        int row = u / (CHWS / 2);
        int hh2 = row % CHH, dd = row / CHH;
        int gd = d0 - 3 + dd, gh = h0 - 3 + hh2;
        int gw0 = w0 - 3 + pair * 2;
        bool okp = (unsigned)gd < 48u && (unsigned)gh < 48u;
        const float* xr0 = xb + (gd * 48 + gh) * 48;
        float v0 = (okp && (unsigned)gw0 < 48u) ? xr0[gw0] : 0.0f;
        float v1 = (okp && (unsigned)(gw0 + 1) < 48u) ? xr0[gw0 + 1] : 0.0f;
        unsigned int packed = (unsigned)f2bf(v0) | ((unsigned)f2bf(v1) << 16);
        *(unsigned int*)&xt[dd][hh2][pair * 2] = packed;
    }
    __syncthreads();

    int hh = tid & 15;                    // output h within tile
    int wg = (tid >> 4) & 1;              // w half (8 outputs)
    int dq = tid >> 5;                    // d quad [0,4): outputs d = dq*4+0..3
    float bias = cb[c];
    f32x2 acc2[2][8];
#pragma unroll
    for (int p = 0; p < 2; ++p)
#pragma unroll
        for (int i = 0; i < 8; ++i) acc2[p][i] = (f32x2){bias, bias};

    const unsigned short* xrow0 = &xt[dq * 4][0][wg * 8];
    for (int kh = 0; kh < 7; ++kh) {
        int hin = hh + kh;
        for (int rr = 0; rr < 10; ++rr) {
            const unsigned short* rp = xrow0 + (rr * CHH + hin) * CHWS;
            uint2 q0 = *(const uint2*)(rp);
            uint2 q1 = *(const uint2*)(rp + 4);
            uint2 q2 = *(const uint2*)(rp + 8);
            unsigned int q3 = *(const unsigned int*)(rp + 12);
            f32x2 xr2[14];
            xr2[0]  = dup2(q0.x << 16); xr2[1]  = dup2(q0.x & 0xffff0000u);
            xr2[2]  = dup2(q0.y << 16); xr2[3]  = dup2(q0.y & 0xffff0000u);
            xr2[4]  = dup2(q1.x << 16); xr2[5]  = dup2(q1.x & 0xffff0000u);
            xr2[6]  = dup2(q1.y << 16); xr2[7]  = dup2(q1.y & 0xffff0000u);
            xr2[8]  = dup2(q2.x << 16); xr2[9]  = dup2(q2.x & 0xffff0000u);
            xr2[10] = dup2(q2.y << 16); xr2[11] = dup2(q2.y & 0xffff0000u);
            xr2[12] = dup2(q3 << 16);   xr2[13] = dup2(q3 & 0xffff0000u);
#pragma unroll
            for (int p = 0; p < 2; ++p) {
                int sv = rr - 2 * p;      // kd for lo half; hi half uses sv-1
                if (sv >= 0 && sv <= 7) {
                    const f32x2* wrow = &wp[sv][kh][0];
#pragma unroll
                    for (int kw = 0; kw < 7; ++kw) {
                        f32x2 w2 = wrow[kw];
#pragma unroll
                        for (int i = 0; i < 8; ++i)
                            asm("v_pk_fma_f32 %0, %1, %2, %0"
                                : "+v"(acc2[p][i]) : "v"(xr2[kw + i]), "v"(w2));
                    }
                }
            }
        }
    }

    float* yb = yc + (long)c * DHW;
#pragma unroll
    for (int p = 0; p < 2; ++p) {
        int dlo = d0 + dq * 4 + 2 * p;
        float* op0 = yb + ((dlo)     * 48 + h0 + hh) * 48 + w0 + wg * 8;
        float* op1 = yb + ((dlo + 1) * 48 + h0 + hh) * 48 + w0 + wg * 8;
        float r0[8], r1[8];
#pragma unroll
        for (int i = 0; i < 8; ++i) { r0[i] = acc2[p][i].x; r1[i] = acc2[p][i].y; }
        *(float4*)op0       = *(float4*)&r0[0];
        *(float4*)(op0 + 4) = *(float4*)&r0[4];
        *(float4*)op1       = *(float4*)&r1[0];
        *(float4*)(op1 + 4) = *(float4*)&r1[4];
    }
}

// ---------------- LayerNorm over C, per-batch NCDHW -> NDHWC (bf16 out) ----------------
__global__ __launch_bounds__(256)
void ln_kernel(const float* __restrict__ yc, const float* __restrict__ g,
               const float* __restrict__ lb, unsigned short* __restrict__ y1)
{
    __shared__ float tile[Cn * Wn];
    __shared__ float mu_s[Wn], rs_s[Wn];
    int dh = blockIdx.x;
    long rowbase = (long)dh * Wn;
    for (int l = threadIdx.x; l < Cn * Wn; l += 256) {
        int c = l / Wn, w = l % Wn;
        tile[l] = yc[rowbase + (long)c * DHW + w];
    }
    __syncthreads();
    if (threadIdx.x < Wn) {
        int w = threadIdx.x;
        float s = 0.f;
        for (int c = 0; c < Cn; ++c) s += tile[c * Wn + w];
        float mu = s * (1.0f / Cn);
        float v = 0.f;
        for (int c = 0; c < Cn; ++c) { float dd = tile[c * Wn + w] - mu; v = fmaf(dd, dd, v); }
        mu_s[w] = mu;
        rs_s[w] = rsqrtf(v * (1.0f / Cn) + 1e-6f);
    }
    __syncthreads();
    long obase = (long)dh * Wn * Cn;
    for (int l = threadIdx.x; l < Cn * Wn; l += 256) {
        int w = l / Cn, c = l % Cn;
        float val = (tile[c * Wn + w] - mu_s[w]) * rs_s[w] * g[c] + lb[c];
        y1[obase + l] = f2bf(val);
    }
}

// ---------------- weight transpose+bf16: Wt[n][k] = bf16(W[k][n]) ----------------
__global__ __launch_bounds__(256)
void wtrans(const float* __restrict__ W, unsigned short* __restrict__ Wt, int K, int N)
{
    int idx = blockIdx.x * 256 + threadIdx.x;
    if (idx >= K * N) return;
    int n = idx / K, k = idx % K;
    Wt[idx] = f2bf(W[(long)k * N + n]);
}

// ---------------- W2 scale+transpose: W2s[n][k] = bf16(W2[k][n]*snx[k]) ----------------
__global__ __launch_bounds__(256)
void wscale(const float* __restrict__ W2, const float* __restrict__ snx,
            unsigned short* __restrict__ W2s)
{
    int idx = blockIdx.x * 256 + threadIdx.x;
    if (idx >= C4 * Cn) return;
    int n = idx / C4, k = idx % C4;
    W2s[idx] = f2bf(W2[(long)k * Cn + n] * snx[k]);
}

// ================= MFMA GEMM: C[M,N] = A[M,K](bf16) @ Bt[N,K](bf16)^T =========
#define BM 128
#define BN 64
#define BK 64

#define GEMM_STAGE(Aptr, Astride, Btptr, Bstride)                               \
    {                                                                           \
        _Pragma("unroll")                                                       \
        for (int i = 0; i < 4; ++i) {                                           \
            int chunk = i * 256 + tid;                                          \
            int r = chunk >> 3, cc = chunk & 7;                                 \
            bf16x8 v = *(const bf16x8*)((Aptr) + (size_t)(m0 + r) * (Astride) + k0 + cc * 8); \
            *(bf16x8*)&Asm[r * BK + ((cc ^ (r & 7)) * 8)] = v;                  \
        }                                                                       \
        _Pragma("unroll")                                                       \
        for (int i = 0; i < 2; ++i) {                                           \
            int chunk = i * 256 + tid;                                          \
            int r = chunk >> 3, cc = chunk & 7;                                 \
            bf16x8 v = *(const bf16x8*)((Btptr) + (size_t)(n0 + r) * (Bstride) + k0 + cc * 8); \
            *(bf16x8*)&Bsm[r * BK + ((cc ^ (r & 7)) * 8)] = v;                  \
        }                                                                       \
    }

#define GEMM_COMPUTE                                                            \
    _Pragma("unroll")                                                           \
    for (int kk = 0; kk < 2; ++kk) {                                            \
        bf16x8 af[4], bfr[2];                                                   \
        _Pragma("unroll")                                                       \
        for (int mi = 0; mi < 4; ++mi) {                                        \
            int r = wm * 64 + mi * 16 + lr;                                     \
            int cc = (kk * 4 + lq) ^ (r & 7);                                   \
            af[mi] = *(const bf16x8*)&Asm[r * BK + cc * 8];                     \
        }                                                                       \
        _Pragma("unroll")                                                       \
        for (int ni = 0; ni < 2; ++ni) {                                        \
            int r = wn * 32 + ni * 16 + lr;                                     \
            int cc = (kk * 4 + lq) ^ (r & 7);                                   \
            bfr[ni] = *(const bf16x8*)&Bsm[r * BK + cc * 8];                    \
        }                                                                       \
        _Pragma("unroll")                                                       \
        for (int mi = 0; mi < 4; ++mi)                                          \
            _Pragma("unroll")                                                   \
            for (int ni = 0; ni < 2; ++ni)                                      \
                acc[mi][ni] = __builtin_amdgcn_mfma_f32_16x16x32_bf16(          \
                    af[mi], bfr[ni], acc[mi][ni], 0, 0, 0);                     \
    }

// ---- GEMM up: y1[M,192] @ w1t[768,192]^T + b1, exact GELU -> y2 bf16 [M,768] ----
__global__ __launch_bounds__(256)
void gemm_up(const unsigned short* __restrict__ A, const unsigned short* __restrict__ Bt,
             const float* __restrict__ bias, unsigned short* __restrict__ Y2)
{
    __shared__ short Asm[BM * BK];
    __shared__ short Bsm[BN * BK];
    int tid = threadIdx.x;
    int lane = tid & 63, wv = tid >> 6;
    int wm = wv >> 1, wn = wv & 1;
    int lr = lane & 15, lq = lane >> 4;
    long m0 = (long)blockIdx.y * BM;
    int n0 = blockIdx.x * BN;

    f32x4 acc[4][2];
#pragma unroll
    for (int mi = 0; mi < 4; ++mi)
#pragma unroll
        for (int ni = 0; ni < 2; ++ni) acc[mi][ni] = (f32x4){0.f, 0.f, 0.f, 0.f};

    for (int k0 = 0; k0 < Cn; k0 += BK) {
        GEMM_STAGE(A, Cn, Bt, Cn);
        __syncthreads();
        GEMM_COMPUTE;
        __syncthreads();
    }

#pragma unroll
    for (int mi = 0; mi < 4; ++mi) {
#pragma unroll
        for (int ni = 0; ni < 2; ++ni) {
            int colg = n0 + wn * 32 + ni * 16 + lr;
            float bb = bias[colg];
            long mbase = m0 + wm * 64 + mi * 16 + lq * 4;
#pragma unroll
            for (int i = 0; i < 4; ++i) {
                float v = acc[mi][ni][i] + bb;
                v = 0.5f * v * (1.0f + erff(v * 0.70710678118654752f));
                Y2[(mbase + i) * C4 + colg] = f2bf(v);
            }
        }
    }
}

// ---- GEMM down: y2[M,768] @ w2s[192,768]^T + beff + x, NDHWC -> NCDHW f32 ----
__global__ __launch_bounds__(256)
void gemm_down(const unsigned short* __restrict__ A, const unsigned short* __restrict__ Bt,
               const float* __restrict__ beff, const float* __restrict__ x,
               float* __restrict__ out)
{
    __shared__ short Asm[BM * BK];
    __shared__ short Bsm[BN * BK];
    int tid = threadIdx.x;
    int lane = tid & 63, wv = tid >> 6;
    int wm = wv >> 1, wn = wv & 1;
    int lr = lane & 15, lq = lane >> 4;
    long m0 = (long)blockIdx.y * BM;
    int n0 = blockIdx.x * BN;

    f32x4 acc[4][2];
#pragma unroll
    for (int mi = 0; mi < 4; ++mi)
#pragma unroll
        for (int ni = 0; ni < 2; ++ni) acc[mi][ni] = (f32x4){0.f, 0.f, 0.f, 0.f};

    for (int k0 = 0; k0 < C4; k0 += BK) {
        GEMM_STAGE(A, C4, Bt, C4);
        __syncthreads();
        GEMM_COMPUTE;
        __syncthreads();
    }

#pragma unroll
    for (int mi = 0; mi < 4; ++mi) {
#pragma unroll
        for (int ni = 0; ni < 2; ++ni) {
            int colg = n0 + wn * 32 + ni * 16 + lr;   // output channel c
            float be = beff[colg];
            long mbase = m0 + wm * 64 + mi * 16 + lq * 4;
            const float* xp = x + (long)colg * DHW + mbase;
            float* op = out + (long)colg * DHW + mbase;
            float4 xv = *(const float4*)xp;
            float4 o;
            o.x = acc[mi][ni][0] + be + xv.x;
            o.y = acc[mi][ni][1] + be + xv.y;
            o.z = acc[mi][ni][2] + be + xv.z;
            o.w = acc[mi][ni][3] + be + xv.w;
            *(float4*)op = o;
        }
    }
}

// ---------------- GRN stats ----------------
__global__ __launch_bounds__(256)
void grn_stats(const unsigned short* __restrict__ Y2, float* __restrict__ partial)
{
    long m0 = (long)blockIdx.x * 128;
    float s0 = 0.f, s1 = 0.f, s2 = 0.f;
    for (int r = 0; r < 128; ++r) {
        const unsigned short* row = Y2 + (m0 + r) * C4;
        float v0 = bf2f(row[threadIdx.x]);       s0 = fmaf(v0, v0, s0);
        float v1 = bf2f(row[threadIdx.x + 256]); s1 = fmaf(v1, v1, s1);
        float v2 = bf2f(row[threadIdx.x + 512]); s2 = fmaf(v2, v2, s2);
    }
    float* p = partial + (long)blockIdx.x * C4;
    p[threadIdx.x] = s0; p[threadIdx.x + 256] = s1; p[threadIdx.x + 512] = s2;
}

// ---------------- GRN reduce ----------------
__global__ __launch_bounds__(256)
void grn_reduce(const float* __restrict__ partial, float* __restrict__ gx2)
{
    int n = blockIdx.x;
    const float* p = partial + n;
    float s = 0.f;
    for (int r = threadIdx.x; r < 864; r += 256) s += p[(long)r * C4];
    __shared__ float red[256];
    red[threadIdx.x] = s; __syncthreads();
    for (int st = 128; st > 0; st >>= 1) {
        if (threadIdx.x < st) red[threadIdx.x] += red[threadIdx.x + st];
        __syncthreads();
    }
    if (threadIdx.x == 0) gx2[n] = red[0];
}

// ---------------- GRN scale ----------------
__global__ __launch_bounds__(256)
void grn_snx(const float* __restrict__ gx2, const float* __restrict__ gamma,
             float* __restrict__ snx)
{
    __shared__ float red[256];
    float gx[3]; float s = 0.f;
#pragma unroll
    for (int i = 0; i < 3; ++i) {
        int n = threadIdx.x + i * 256;
        gx[i] = sqrtf(gx2[n]);
        s += gx[i];
    }
    red[threadIdx.x] = s; __syncthreads();
    for (int st = 128; st > 0; st >>= 1) {
        if (threadIdx.x < st) red[threadIdx.x] += red[threadIdx.x + st];
        __syncthreads();
    }
    float inv = 1.0f / (red[0] * (1.0f / C4) + 1e-6f);
#pragma unroll
    for (int i = 0; i < 3; ++i) {
        int n = threadIdx.x + i * 256;
        snx[n] = 1.0f + gamma[n] * gx[i] * inv;
    }
}

// ---------------- effective down-bias ----------------
__global__ __launch_bounds__(192)
void bias_eff_k(const float* __restrict__ beta, const float* __restrict__ W2,
                const float* __restrict__ b2, float* __restrict__ beff)
{
    int j = threadIdx.x;
    float s = b2[j];
    for (int k = 0; k < C4; ++k) s = fmaf(beta[k], W2[k * Cn + j], s);
    beff[j] = s;
}

extern "C" void kernel_launch(void* const* d_in, const int* in_sizes, int n_in,
                              void* d_out, int out_size, void* d_ws, size_t ws_size,
                              hipStream_t stream) {
    const float* x      = (const float*)d_in[0];
    const float* conv_w = (const float*)d_in[1];
    const float* conv_b = (const float*)d_in[2];
    const float* ln_g   = (const float*)d_in[3];
    const float* ln_b   = (const float*)d_in[4];
    const float* w1     = (const float*)d_in[5];
    const float* b1     = (const float*)d_in[6];
    const float* gg     = (const float*)d_in[7];
    const float* gb     = (const float*)d_in[8];
    const float* w2     = (const float*)d_in[9];
    const float* b2     = (const float*)d_in[10];
    float* out = (float*)d_out;
    char* ws = (char*)d_ws;

    unsigned short* y2  = (unsigned short*)(ws);                  // [M][768] bf16, overlaps yc
    float*          yc  = (float*)(ws);                           // [192][DHW] f32
    unsigned short* y1  = (unsigned short*)(ws + 169869312L);     // [M][192] bf16
    float*     partial  = (float*)(ws + 212336640L);              // [864][768] f32
    unsigned short* w1t = (unsigned short*)(ws + 214990848L);     // [768][192] bf16
    unsigned short* w2s = (unsigned short*)(ws + 215285760L);     // [192][768] bf16
    float*         gx2  = (float*)(ws + 215580672L);
    float*         snx  = (float*)(ws + 215583744L);
    float*        beff  = (float*)(ws + 215586816L);

    bias_eff_k<<<1, 192, 0, stream>>>(gb, w2, b2, beff);
    wtrans<<<(Cn * C4 + 255) / 256, 256, 0, stream>>>(w1, w1t, Cn, C4);

    for (int b = 0; b < Bn; ++b) {
        const float* xb = x + (size_t)b * CDHW;
        float* outb = out + (size_t)b * CDHW;
        dim3 gc(27, Cn);                  // 3x3x3 spatial tiles of 16^3
        conv_dw<<<gc, 128, 0, stream>>>(xb, conv_w, conv_b, yc);
        ln_kernel<<<Dn * Hn, 256, 0, stream>>>(yc, ln_g, ln_b, y1);
        dim3 gu(C4 / BN, DHW / BM);
        gemm_up<<<gu, 256, 0, stream>>>(y1, w1t, b1, y2);
        grn_stats<<<DHW / 128, 256, 0, stream>>>(y2, partial);
        grn_reduce<<<C4, 256, 0, stream>>>(partial, gx2);
        grn_snx<<<1, 256, 0, stream>>>(gx2, gg, snx);
        wscale<<<(Cn * C4 + 255) / 256, 256, 0, stream>>>(w2, snx, w2s);
        dim3 gd(Cn / BN, DHW / BM);
        gemm_down<<<gd, 256, 0, stream>>>(y2, w2s, beff, xb, outb);
    }
}